// Round 18
// baseline (311.232 us; speedup 1.0000x reference)
//
#include <hip/hip_runtime.h>
#include <stdint.h>

#define N_NODES_C 262144
#define N_EDGES_C 2097152
#define NB_C      8192      // graphs
#define NEG_SLOPE_C 0.2f

#define NBKT 1024           // dst buckets
#define NPB  256            // nodes per bucket
#define CHUNK 8192          // edges per binning block
#define NBINBLK 256         // N_EDGES_C / CHUNK
#define FSTR 260            // padded LDS f-row stride

typedef __attribute__((ext_vector_type(4))) float f32x4;
typedef __attribute__((ext_vector_type(8))) short short8;
typedef __attribute__((ext_vector_type(4))) unsigned short us4;
typedef unsigned int u32;

static __device__ __forceinline__ unsigned short f2bf(float f) {
    unsigned int u = __builtin_bit_cast(unsigned int, f);
    unsigned int r = (u + 0x7FFFu + ((u >> 16) & 1u)) >> 16;
    return (unsigned short)r;
}
static __device__ __forceinline__ float bf2f(unsigned short u) {
    unsigned int x = ((unsigned int)u) << 16;
    return __builtin_bit_cast(float, x);
}

// ---------------- utility ----------------
__global__ void zero_u32(u32* __restrict__ p, int n) {
    int i = blockIdx.x * blockDim.x + threadIdx.x;
    int stride = gridDim.x * blockDim.x;
    for (int k = i; k < n; k += stride) p[k] = 0u;
}

__global__ void transpose_cast(const float* __restrict__ in,
                               unsigned short* __restrict__ out, int R, int Cc) {
    int i = blockIdx.x * blockDim.x + threadIdx.x;
    if (i < R * Cc) {
        int r = i / Cc, c = i % Cc;
        out[(size_t)c * R + r] = f2bf(in[i]);
    }
}

// ---------------- CSR build: block-owned two-level bucket sort ----------------
__global__ __launch_bounds__(1024) void bin_count(const int* __restrict__ dst,
                                                  u32* __restrict__ gtotal,
                                                  u32* __restrict__ bhist) {
    __shared__ u32 hist[NBKT];
    for (int i = threadIdx.x; i < NBKT; i += 1024) hist[i] = 0u;
    __syncthreads();
    const int e0 = blockIdx.x * CHUNK;
    for (int i = threadIdx.x; i < CHUNK; i += 1024)
        atomicAdd(&hist[((u32)dst[e0 + i]) >> 8], 1u);
    __syncthreads();
    for (int i = threadIdx.x; i < NBKT; i += 1024) {
        u32 c = hist[i];
        bhist[(size_t)blockIdx.x * NBKT + i] = c;
        if (c) atomicAdd(&gtotal[i], c);
    }
}

__global__ __launch_bounds__(256) void bin_scan(const u32* __restrict__ gtotal,
                                                u32* __restrict__ cbase,
                                                u32* __restrict__ gcursor) {
    __shared__ u32 sd[256];
    const int t = threadIdx.x;
    uint4 c = ((const uint4*)gtotal)[t];
    u32 s = c.x + c.y + c.z + c.w;
    sd[t] = s;
    __syncthreads();
    for (int off = 1; off < 256; off <<= 1) {
        u32 v = (t >= off) ? sd[t - off] : 0u;
        __syncthreads();
        sd[t] += v;
        __syncthreads();
    }
    u32 ex = sd[t] - s;
    u32 b0 = ex, b1 = ex + c.x, b2 = b1 + c.y, b3 = b2 + c.z;
    cbase[t * 4 + 0] = b0; gcursor[t * 4 + 0] = b0;
    cbase[t * 4 + 1] = b1; gcursor[t * 4 + 1] = b1;
    cbase[t * 4 + 2] = b2; gcursor[t * 4 + 2] = b2;
    cbase[t * 4 + 3] = b3; gcursor[t * 4 + 3] = b3;
    if (t == 255) cbase[NBKT] = N_EDGES_C;
}

__global__ __launch_bounds__(1024) void bin_scatter(const int* __restrict__ src,
                                                    const int* __restrict__ dst,
                                                    const u32* __restrict__ bhist,
                                                    u32* __restrict__ gcursor,
                                                    u32* __restrict__ packed) {
    __shared__ u32 gpos[NBKT];
    __shared__ u32 cur[NBKT];
    for (int i = threadIdx.x; i < NBKT; i += 1024) {
        u32 c = bhist[(size_t)blockIdx.x * NBKT + i];
        gpos[i] = c ? atomicAdd(&gcursor[i], c) : 0u;
        cur[i] = 0u;
    }
    __syncthreads();
    const int e0 = blockIdx.x * CHUNK;
    for (int i = threadIdx.x; i < CHUNK; i += 1024) {
        u32 d = (u32)dst[e0 + i];
        u32 b = d >> 8;
        u32 r = atomicAdd(&cur[b], 1u);
        packed[gpos[b] + r] = (u32)src[e0 + i] | ((d & 255u) << 18);
    }
}

__global__ __launch_bounds__(256) void csr_convert(const u32* __restrict__ cbase,
                                                   const u32* __restrict__ packed,
                                                   u32* __restrict__ row_start,
                                                   int* __restrict__ sorted_src) {
    __shared__ u32 cnt[NPB];
    __shared__ u32 pos[NPB];
    const int b = blockIdx.x;
    const u32 beg = cbase[b], end = cbase[b + 1];
    const int t = threadIdx.x;
    cnt[t] = 0u;
    __syncthreads();
    for (u32 i = beg + t; i < end; i += 256)
        atomicAdd(&cnt[packed[i] >> 18], 1u);
    __syncthreads();
    pos[t] = cnt[t];
    __syncthreads();
    for (int off = 1; off < 256; off <<= 1) {
        u32 v = (t >= off) ? pos[t - off] : 0u;
        __syncthreads();
        pos[t] += v;
        __syncthreads();
    }
    const u32 ex = pos[t] - cnt[t];
    row_start[b * NPB + t] = beg + ex;
    __syncthreads();
    cnt[t] = ex;
    __syncthreads();
    for (u32 i = beg + t; i < end; i += 256) {
        u32 p = packed[i];
        u32 r = atomicAdd(&cnt[p >> 18], 1u);
        sorted_src[beg + r] = (int)(p & 0x3FFFFu);
    }
    if (b == 0 && t == 0) row_start[N_NODES_C] = N_EDGES_C;
}

// ---------------- node transform via MFMA: h = X @ W, a_s, a_d ----------------
template <int LAYER>
__global__ __launch_bounds__(256) void transform_mfma(
    const void* __restrict__ xin_,
    const unsigned short* __restrict__ Wt,   // bf16 [64][64]: Wt[o][k]
    const float* __restrict__ att_s, const float* __restrict__ att_d,
    const float* __restrict__ bias_in,       // layer2 only: b1
    unsigned short* __restrict__ h_bf,
    float* __restrict__ a_s, float* __restrict__ a_d)
{
    const int lane = threadIdx.x & 63;
    const int wid  = threadIdx.x >> 6;
    const int col  = lane & 15;
    const int kl   = lane >> 4;   // 0..3

    short8 bfr[4][2];
    #pragma unroll
    for (int t = 0; t < 4; ++t)
        #pragma unroll
        for (int kh = 0; kh < 2; ++kh)
            bfr[t][kh] = *(const short8*)(Wt + (t * 16 + col) * 64 + kh * 32 + kl * 8);

    float attS[4], attD[4];
    #pragma unroll
    for (int t = 0; t < 4; ++t) {
        attS[t] = att_s[t * 16 + col];
        attD[t] = att_d[t * 16 + col];
    }
    float bofs[2][8];
    if constexpr (LAYER == 2) {
        #pragma unroll
        for (int kh = 0; kh < 2; ++kh)
            #pragma unroll
            for (int j = 0; j < 8; ++j) bofs[kh][j] = bias_in[kh * 32 + kl * 8 + j];
    }

    const int g = blockIdx.x * 4 + wid;
    const int arow = g * 16 + col;
    short8 af[2];
    if constexpr (LAYER == 1) {
        const float* xp = (const float*)xin_ + (size_t)arow * 64;
        #pragma unroll
        for (int kh = 0; kh < 2; ++kh) {
            f32x4 v0 = *(const f32x4*)(xp + kh * 32 + kl * 8);
            f32x4 v1 = *(const f32x4*)(xp + kh * 32 + kl * 8 + 4);
            short8 a;
            #pragma unroll
            for (int j = 0; j < 4; ++j) {
                a[j]     = (short)f2bf(v0[j]);
                a[4 + j] = (short)f2bf(v1[j]);
            }
            af[kh] = a;
        }
    } else {
        const unsigned short* xp = (const unsigned short*)xin_ + (size_t)arow * 64;
        #pragma unroll
        for (int kh = 0; kh < 2; ++kh) {
            short8 raw = *(const short8*)(xp + kh * 32 + kl * 8);
            short8 a;
            #pragma unroll
            for (int j = 0; j < 8; ++j)
                a[j] = (short)f2bf(bf2f((unsigned short)raw[j]) + bofs[kh][j]);
            af[kh] = a;
        }
    }

    f32x4 acc[4];
    #pragma unroll
    for (int t = 0; t < 4; ++t) {
        f32x4 d = {0.f, 0.f, 0.f, 0.f};
        d = __builtin_amdgcn_mfma_f32_16x16x32_bf16(af[0], bfr[t][0], d, 0, 0, 0);
        d = __builtin_amdgcn_mfma_f32_16x16x32_bf16(af[1], bfr[t][1], d, 0, 0, 0);
        acc[t] = d;
    }

    float ps[4] = {0.f, 0.f, 0.f, 0.f}, pd[4] = {0.f, 0.f, 0.f, 0.f};
    #pragma unroll
    for (int t = 0; t < 4; ++t) {
        #pragma unroll
        for (int j = 0; j < 4; ++j) {
            int node = g * 16 + kl * 4 + j;
            h_bf[(size_t)node * 64 + t * 16 + col] = f2bf(acc[t][j]);
            ps[j] += acc[t][j] * attS[t];
            pd[j] += acc[t][j] * attD[t];
        }
    }
    #pragma unroll
    for (int m = 1; m < 16; m <<= 1) {
        #pragma unroll
        for (int j = 0; j < 4; ++j) {
            ps[j] += __shfl_xor(ps[j], m, 64);
            pd[j] += __shfl_xor(pd[j], m, 64);
        }
    }
    if (col == 0) {
        #pragma unroll
        for (int j = 0; j < 4; ++j) {
            int node = g * 16 + kl * 4 + j;
            a_s[node] = ps[j];
            a_d[node] = pd[j];
        }
    }
}

// ---------------- per-node fallback (any degree) ----------------
static __device__ __forceinline__ void agg_one_node(
    int node, u32 beg, u32 end, int lane, int sub, int c4,
    const int* __restrict__ sorted_src, const float* __restrict__ a_s,
    const float* __restrict__ a_d, const unsigned short* __restrict__ h_bf,
    const float* __restrict__ bias_out, unsigned short* __restrict__ agg_bf)
{
    f32x4 acc = {0.f, 0.f, 0.f, 0.f};
    if (end > beg) {
        const float ad = a_d[node];
        float l = 0.f;
        for (u32 base = beg; base < end; base += 64) {
            u32 i = base + lane;
            bool valid = i < end;
            int s = valid ? sorted_src[i] : 0;
            float e = valid ? a_s[s] + ad : 0.f;
            e = e > 0.f ? e : NEG_SLOPE_C * e;
            float p = valid ? __expf(e) : 0.f;
            #pragma unroll
            for (int off = 32; off; off >>= 1) p += __shfl_xor(p, off, 64);
            l += p;
        }
        const float inv = 1.f / l;
        for (u32 base = beg; base < end; base += 64) {
            u32 i = base + lane;
            bool valid = i < end;
            int s = valid ? sorted_src[i] : 0;
            float e = valid ? a_s[s] + ad : 0.f;
            e = e > 0.f ? e : NEG_SLOPE_C * e;
            float p = valid ? __expf(e) * inv : 0.f;
            int c2 = (int)min(64u, end - base);
            for (int t = 0; t < c2; t += 4) {
                int j = t + sub;
                float al = __shfl(p, j, 64);     // unconditional
                int   sj = __shfl(s, j, 64);     // unconditional
                if (j >= c2) al = 0.f;
                us4 hv = *(const us4*)(h_bf + (size_t)sj * 64 + c4);
                acc[0] += al * bf2f(hv[0]);
                acc[1] += al * bf2f(hv[1]);
                acc[2] += al * bf2f(hv[2]);
                acc[3] += al * bf2f(hv[3]);
            }
        }
    }
    #pragma unroll
    for (int k = 0; k < 4; ++k) {
        acc[k] += __shfl_xor(acc[k], 16, 64);
        acc[k] += __shfl_xor(acc[k], 32, 64);
    }
    if (sub == 0) {
        us4 o;
        if (bias_out) {
            #pragma unroll
            for (int k = 0; k < 4; ++k) o[k] = f2bf(acc[k] + bias_out[c4 + k]);
        } else {
            #pragma unroll
            for (int k = 0; k < 4; ++k) o[k] = f2bf(acc[k]);
        }
        *(us4*)(agg_bf + (size_t)node * 64 + c4) = o;
    }
}

// ---------------- fused GAT aggregate: 3-tier (at gather floor) ----------------
__global__ __launch_bounds__(256) void gat_aggregate(
    const u32* __restrict__ row_start, const int* __restrict__ sorted_src,
    const float* __restrict__ a_s, const float* __restrict__ a_d,
    const unsigned short* __restrict__ h_bf, const float* __restrict__ bias_out,
    unsigned short* __restrict__ agg_bf)
{
    const int lane = threadIdx.x & 63;
    const int sub  = lane >> 4;        // slot = owned node index
    const int j    = lane & 15;        // slot-local edge / channel-quad index
    const int c4   = j * 4;            // channel quad base
    const int wid = (blockIdx.x * blockDim.x + threadIdx.x) >> 6;  // 65536 waves
    const int n0 = wid * 4;

    uint4 r4 = *(const uint4*)(row_start + n0);
    const u32 rs0 = r4.x, rs1 = r4.y, rs2 = r4.z, rs3 = r4.w;
    const u32 rs4 = row_start[n0 + 4];
    const int d0 = (int)(rs1 - rs0), d1 = (int)(rs2 - rs1);
    const int d2 = (int)(rs3 - rs2), d3 = (int)(rs4 - rs3);
    const int mx = max(max(d0, d1), max(d2, d3));
    const u32 beg = rs0, end = rs4;
    const int tot = (int)(end - beg);

    if (mx <= 16) {
        // ---- tier 1: slot-local softmax + per-slot-bounded PV ----
        const u32 rlo = (sub == 0) ? rs0 : (sub == 1) ? rs1 : (sub == 2) ? rs2 : rs3;
        const int ck  = (sub == 0) ? d0  : (sub == 1) ? d1  : (sub == 2) ? d2  : d3;
        const bool valid = j < ck;
        int s_own = valid ? sorted_src[rlo + j] : 0;
        float e = valid ? a_s[s_own] + a_d[n0 + sub] : 0.f;
        e = e > 0.f ? e : NEG_SLOPE_C * e;
        const float p = valid ? __expf(e) : 0.f;
        float l = p;
        l += __shfl_xor(l, 1, 64);
        l += __shfl_xor(l, 2, 64);
        l += __shfl_xor(l, 4, 64);
        l += __shfl_xor(l, 8, 64);
        const float alpha = valid ? p * (1.f / l) : 0.f;

        const int base = sub * 16;
        f32x4 acc = {0.f, 0.f, 0.f, 0.f};
        for (int t = 0; t < ck; t += 2) {
            float al0 = __shfl(alpha, base + t, 64);
            int   s0  = __shfl(s_own, base + t, 64);
            float al1 = __shfl(alpha, base + t + 1, 64);
            int   s1  = __shfl(s_own, base + t + 1, 64);
            if (t + 1 >= ck) al1 = 0.f;       // odd-ck guard (after shuffle)
            us4 h0 = *(const us4*)(h_bf + (size_t)s0 * 64 + c4);
            us4 h1 = *(const us4*)(h_bf + (size_t)s1 * 64 + c4);
            acc[0] += al0 * bf2f(h0[0]) + al1 * bf2f(h1[0]);
            acc[1] += al0 * bf2f(h0[1]) + al1 * bf2f(h1[1]);
            acc[2] += al0 * bf2f(h0[2]) + al1 * bf2f(h1[2]);
            acc[3] += al0 * bf2f(h0[3]) + al1 * bf2f(h1[3]);
        }

        us4 o;
        if (bias_out) {
            #pragma unroll
            for (int q = 0; q < 4; ++q) o[q] = f2bf(acc[q] + bias_out[c4 + q]);
        } else {
            #pragma unroll
            for (int q = 0; q < 4; ++q) o[q] = f2bf(acc[q]);
        }
        *(us4*)(agg_bf + (size_t)(n0 + sub) * 64 + c4) = o;
        return;
    }

    if (tot > 64) {
        agg_one_node(n0 + 0, rs0, rs1, lane, sub, c4, sorted_src, a_s, a_d, h_bf, bias_out, agg_bf);
        agg_one_node(n0 + 1, rs1, rs2, lane, sub, c4, sorted_src, a_s, a_d, h_bf, bias_out, agg_bf);
        agg_one_node(n0 + 2, rs2, rs3, lane, sub, c4, sorted_src, a_s, a_d, h_bf, bias_out, agg_bf);
        agg_one_node(n0 + 3, rs3, rs4, lane, sub, c4, sorted_src, a_s, a_d, h_bf, bias_out, agg_bf);
        return;
    }

    // ---- tier 2: union-lane path ----
    const u32 i = beg + (u32)lane;
    const bool valid = i < end;
    int s = valid ? sorted_src[i] : 0;
    const u32 r1 = rs1 - beg, r2 = rs2 - beg, r3 = rs3 - beg;
    const int nid = (int)((u32)lane >= r1) + (int)((u32)lane >= r2) + (int)((u32)lane >= r3);
    float e = valid ? a_s[s] + a_d[n0 + nid] : 0.f;
    e = e > 0.f ? e : NEG_SLOPE_C * e;
    const float p = valid ? __expf(e) : 0.f;

    float l0 = (nid == 0) ? p : 0.f;
    float l1 = (nid == 1) ? p : 0.f;
    float l2 = (nid == 2) ? p : 0.f;
    float l3 = (nid == 3) ? p : 0.f;
    #pragma unroll
    for (int off = 32; off; off >>= 1) {
        l0 += __shfl_xor(l0, off, 64);
        l1 += __shfl_xor(l1, off, 64);
        l2 += __shfl_xor(l2, off, 64);
        l3 += __shfl_xor(l3, off, 64);
    }
    const float i0 = 1.f / l0, i1 = 1.f / l1, i2 = 1.f / l2, i3 = 1.f / l3;
    const float invk = (nid < 2) ? (nid == 0 ? i0 : i1) : (nid == 2 ? i2 : i3);
    const float alpha = valid ? p * invk : 0.f;

    #pragma unroll
    for (int k = 0; k < 4; ++k) {
        const u32 rloK = (k == 0) ? rs0 : (k == 1) ? rs1 : (k == 2) ? rs2 : rs3;
        const u32 rhiK = (k == 0) ? rs1 : (k == 1) ? rs2 : (k == 2) ? rs3 : rs4;
        const int rb = (int)(rloK - beg);
        const int ck = (int)(rhiK - rloK);
        f32x4 acc = {0.f, 0.f, 0.f, 0.f};
        for (int t = 0; t < ck; t += 8) {
            const int j0 = rb + t + sub;
            const int j1 = j0 + 4;
            float al0 = __shfl(alpha, j0, 64);   // unconditional (convergent)
            int   s0  = __shfl(s, j0, 64);
            float al1 = __shfl(alpha, j1, 64);
            int   s1  = __shfl(s, j1, 64);
            if (t + sub >= ck)     al0 = 0.f;    // guard AFTER the shuffle
            if (t + 4 + sub >= ck) al1 = 0.f;
            us4 h0 = *(const us4*)(h_bf + (size_t)s0 * 64 + c4);
            us4 h1 = *(const us4*)(h_bf + (size_t)s1 * 64 + c4);
            acc[0] += al0 * bf2f(h0[0]) + al1 * bf2f(h1[0]);
            acc[1] += al0 * bf2f(h0[1]) + al1 * bf2f(h1[1]);
            acc[2] += al0 * bf2f(h0[2]) + al1 * bf2f(h1[2]);
            acc[3] += al0 * bf2f(h0[3]) + al1 * bf2f(h1[3]);
        }
        #pragma unroll
        for (int q = 0; q < 4; ++q) {
            acc[q] += __shfl_xor(acc[q], 16, 64);
            acc[q] += __shfl_xor(acc[q], 32, 64);
        }
        if (sub == 0) {
            us4 o;
            if (bias_out) {
                #pragma unroll
                for (int q = 0; q < 4; ++q) o[q] = f2bf(acc[q] + bias_out[c4 + q]);
            } else {
                #pragma unroll
                for (int q = 0; q < 4; ++q) o[q] = f2bf(acc[q]);
            }
            *(us4*)(agg_bf + (size_t)(n0 + k) * 64 + c4) = o;
        }
    }
}

// ---------------- FC head (fc1 + fc2 fused, 512 blocks x 16 rows) ----------------
// agg_bf already contains (+b2). f = relu(agg @ Wf1 + bf1) staged in LDS;
// out = f @ Wf2 + bf2 computed in-block (block = 16 graphs).
// 512 threads = 8 waves = 4 col-groups x 2 K-halves; 2 blocks/CU co-resident.
__global__ __launch_bounds__(512) void fc_head(
    const unsigned short* __restrict__ agg_bf,
    const unsigned short* __restrict__ Wf1t,  // bf16 [256][2048]
    const float* __restrict__ bf1,
    const float* __restrict__ Wf2,            // [256][32]
    const float* __restrict__ bf2v,
    float* __restrict__ out)                  // [8192][32]
{
    __shared__ float shmem[4 * 64 * 17];      // 17.4 KB: partials, then f-rows
    const int lane = threadIdx.x & 63;
    const int w    = threadIdx.x >> 6;   // 0..7
    const int cg   = w & 3;              // col group: cols cg*64 .. +63
    const int kh   = w >> 2;             // K half
    const int col  = lane & 15;
    const int kl   = lane >> 4;
    const int rbase = blockIdx.x * 16;   // 512 blocks

    const int kbase = kh * 1024 + kl * 8;
    const unsigned short* a0p = agg_bf + (size_t)(rbase + col) * 2048 + kbase;
    const unsigned short* bp0 = Wf1t + (size_t)(cg * 64 + col) * 2048 + kbase;
    const unsigned short* bp1 = bp0 + 16 * 2048;
    const unsigned short* bp2 = bp0 + 32 * 2048;
    const unsigned short* bp3 = bp0 + 48 * 2048;

    f32x4 acc[4];
    #pragma unroll
    for (int ct = 0; ct < 4; ++ct) acc[ct] = (f32x4){0.f, 0.f, 0.f, 0.f};

    short8 a0 = *(const short8*)a0p;
    short8 b0 = *(const short8*)bp0, b1 = *(const short8*)bp1;
    short8 b2 = *(const short8*)bp2, b3 = *(const short8*)bp3;

    for (int ks = 0; ks < 32; ++ks) {
        const short8 ca0 = a0, cb0 = b0, cb1 = b1, cb2 = b2, cb3 = b3;
        if (ks < 31) {                          // prefetch next K-step
            const int off = (ks + 1) * 32;
            a0 = *(const short8*)(a0p + off);
            b0 = *(const short8*)(bp0 + off);
            b1 = *(const short8*)(bp1 + off);
            b2 = *(const short8*)(bp2 + off);
            b3 = *(const short8*)(bp3 + off);
        }
        acc[0] = __builtin_amdgcn_mfma_f32_16x16x32_bf16(ca0, cb0, acc[0], 0, 0, 0);
        acc[1] = __builtin_amdgcn_mfma_f32_16x16x32_bf16(ca0, cb1, acc[1], 0, 0, 0);
        acc[2] = __builtin_amdgcn_mfma_f32_16x16x32_bf16(ca0, cb2, acc[2], 0, 0, 0);
        acc[3] = __builtin_amdgcn_mfma_f32_16x16x32_bf16(ca0, cb3, acc[3], 0, 0, 0);
    }

    // phase A: kh==1 publishes partials (stride 17: 16 floats + pad)
    if (kh == 1) {
        #pragma unroll
        for (int ct = 0; ct < 4; ++ct)
            #pragma unroll
            for (int q = 0; q < 4; ++q)
                shmem[cg * (64 * 17) + lane * 17 + ct * 4 + q] = acc[ct][q];
    }
    __syncthreads();
    // phase B: kh==0 combines + bias + relu (registers)
    if (kh == 0) {
        #pragma unroll
        for (int ct = 0; ct < 4; ++ct) {
            const int ocol = cg * 64 + ct * 16 + col;
            const float bias = bf1[ocol];
            #pragma unroll
            for (int q = 0; q < 4; ++q) {
                float v = acc[ct][q]
                        + shmem[cg * (64 * 17) + lane * 17 + ct * 4 + q]
                        + bias;
                acc[ct][q] = v > 0.f ? v : 0.f;
            }
        }
    }
    __syncthreads();   // partial reads done; shmem free for reuse
    // phase C: kh==0 writes f-rows (padded stride FSTR); 16*260 = 4160 < 4352
    if (kh == 0) {
        #pragma unroll
        for (int ct = 0; ct < 4; ++ct) {
            const int ocol = cg * 64 + ct * 16 + col;
            #pragma unroll
            for (int q = 0; q < 4; ++q) {
                int row = kl * 4 + q;          // block-relative 0..15
                shmem[row * FSTR + ocol] = acc[ct][q];
            }
        }
    }
    __syncthreads();
    // phase D: fc2 — 512 outputs, 1 per thread
    {
        const int b = threadIdx.x >> 5, o = threadIdx.x & 31;
        float a2 = bf2v[o];
        const float* fp = shmem + b * FSTR;
        for (int jj = 0; jj < 256; jj += 4) {
            a2 += fp[jj + 0] * Wf2[(jj + 0) * 32 + o];
            a2 += fp[jj + 1] * Wf2[(jj + 1) * 32 + o];
            a2 += fp[jj + 2] * Wf2[(jj + 2) * 32 + o];
            a2 += fp[jj + 3] * Wf2[(jj + 3) * 32 + o];
        }
        out[(size_t)(rbase + b) * 32 + o] = a2;
    }
}

// ---------------- launch ----------------
extern "C" void kernel_launch(void* const* d_in, const int* in_sizes, int n_in,
                              void* d_out, int out_size, void* d_ws, size_t ws_size,
                              hipStream_t stream)
{
    const float* x    = (const float*)d_in[0];
    const int*   ei   = (const int*)d_in[1];
    const float* W1   = (const float*)d_in[2];
    const float* as1  = (const float*)d_in[3];
    const float* ad1  = (const float*)d_in[4];
    const float* b1   = (const float*)d_in[5];
    const float* W2   = (const float*)d_in[6];
    const float* as2  = (const float*)d_in[7];
    const float* ad2  = (const float*)d_in[8];
    const float* b2   = (const float*)d_in[9];
    const float* Wf1  = (const float*)d_in[10];
    const float* bf1  = (const float*)d_in[11];
    const float* Wf2  = (const float*)d_in[12];
    const float* bf2v = (const float*)d_in[13];

    const int* src = ei;
    const int* dst = ei + N_EDGES_C;

    char* ws = (char*)d_ws;
    unsigned short* h_bf   = (unsigned short*)ws; ws += (size_t)N_NODES_C * 64 * 2;
    unsigned short* agg_bf = (unsigned short*)ws; ws += (size_t)N_NODES_C * 64 * 2;
    float* a_s          = (float*)ws;          ws += (size_t)N_NODES_C * 4;
    float* a_d          = (float*)ws;          ws += (size_t)N_NODES_C * 4;
    u32* row_start      = (u32*)ws;            ws += (size_t)(N_NODES_C + 4) * 4;
    int* sorted_src     = (int*)ws;            ws += (size_t)N_EDGES_C * 4;
    u32* packed         = (u32*)ws;            ws += (size_t)N_EDGES_C * 4;
    u32* bhist          = (u32*)ws;            ws += (size_t)NBINBLK * NBKT * 4;
    u32* gtotal         = (u32*)ws;            ws += NBKT * 4;
    u32* cbase          = (u32*)ws;            ws += (NBKT + 4) * 4;
    u32* gcursor        = (u32*)ws;            ws += NBKT * 4;
    unsigned short* Wt1 = (unsigned short*)ws; ws += 64 * 64 * 2;
    unsigned short* Wt2 = (unsigned short*)ws; ws += 64 * 64 * 2;
    unsigned short* Wf1t = (unsigned short*)ws; ws += (size_t)256 * 2048 * 2;

    // ---- weight transposes (bf16) ----
    transpose_cast<<<16, 256, 0, stream>>>(W1, Wt1, 64, 64);
    transpose_cast<<<16, 256, 0, stream>>>(W2, Wt2, 64, 64);
    transpose_cast<<<2048, 256, 0, stream>>>(Wf1, Wf1t, 2048, 256);

    // ---- CSR build: block-owned bucket sort (shared by both layers) ----
    zero_u32<<<1, 256, 0, stream>>>(gtotal, NBKT);
    bin_count<<<NBINBLK, 1024, 0, stream>>>(dst, gtotal, bhist);
    bin_scan<<<1, 256, 0, stream>>>(gtotal, cbase, gcursor);
    bin_scatter<<<NBINBLK, 1024, 0, stream>>>(src, dst, bhist, gcursor, packed);
    csr_convert<<<NBKT, 256, 0, stream>>>(cbase, packed, row_start, sorted_src);

    // ---- layer 1 ----
    transform_mfma<1><<<4096, 256, 0, stream>>>(x, Wt1, as1, ad1, nullptr, h_bf, a_s, a_d);
    gat_aggregate<<<16384, 256, 0, stream>>>(row_start, sorted_src, a_s, a_d, h_bf,
                                             nullptr, agg_bf);

    // ---- layer 2 (fold b2 into aggregate output for fc1) ----
    transform_mfma<2><<<4096, 256, 0, stream>>>(agg_bf, Wt2, as2, ad2, b1, h_bf, a_s, a_d);
    gat_aggregate<<<16384, 256, 0, stream>>>(row_start, sorted_src, a_s, a_d, h_bf,
                                             b2, agg_bf);

    // ---- FC head (fc1 + fc2 fused) ----
    fc_head<<<512, 512, 0, stream>>>(agg_bf, Wf1t, bf1, Wf2, bf2v, (float*)d_out);
}

// Round 19
// 282.321 us; speedup vs baseline: 1.1024x; 1.1024x over previous
//
#include <hip/hip_runtime.h>
#include <stdint.h>

#define N_NODES_C 262144
#define N_EDGES_C 2097152
#define NB_C      8192      // graphs
#define NEG_SLOPE_C 0.2f

#define NBKT 1024           // dst buckets
#define NPB  256            // nodes per bucket
#define CHUNK 8192          // edges per binning block
#define NBINBLK 256         // N_EDGES_C / CHUNK
#define FSTR 260            // padded LDS f-row stride
#define PSTR 33             // padded partial stride (32 floats + 1)
#define PREG (4 * 64 * PSTR)  // one partial region: cg x lane x PSTR

typedef __attribute__((ext_vector_type(4))) float f32x4;
typedef __attribute__((ext_vector_type(8))) short short8;
typedef __attribute__((ext_vector_type(4))) unsigned short us4;
typedef unsigned int u32;

static __device__ __forceinline__ unsigned short f2bf(float f) {
    unsigned int u = __builtin_bit_cast(unsigned int, f);
    unsigned int r = (u + 0x7FFFu + ((u >> 16) & 1u)) >> 16;
    return (unsigned short)r;
}
static __device__ __forceinline__ float bf2f(unsigned short u) {
    unsigned int x = ((unsigned int)u) << 16;
    return __builtin_bit_cast(float, x);
}

// ---------------- utility ----------------
__global__ void zero_u32(u32* __restrict__ p, int n) {
    int i = blockIdx.x * blockDim.x + threadIdx.x;
    int stride = gridDim.x * blockDim.x;
    for (int k = i; k < n; k += stride) p[k] = 0u;
}

__global__ void transpose_cast(const float* __restrict__ in,
                               unsigned short* __restrict__ out, int R, int Cc) {
    int i = blockIdx.x * blockDim.x + threadIdx.x;
    if (i < R * Cc) {
        int r = i / Cc, c = i % Cc;
        out[(size_t)c * R + r] = f2bf(in[i]);
    }
}

// ---------------- CSR build: block-owned two-level bucket sort ----------------
__global__ __launch_bounds__(1024) void bin_count(const int* __restrict__ dst,
                                                  u32* __restrict__ gtotal,
                                                  u32* __restrict__ bhist) {
    __shared__ u32 hist[NBKT];
    for (int i = threadIdx.x; i < NBKT; i += 1024) hist[i] = 0u;
    __syncthreads();
    const int e0 = blockIdx.x * CHUNK;
    for (int i = threadIdx.x; i < CHUNK; i += 1024)
        atomicAdd(&hist[((u32)dst[e0 + i]) >> 8], 1u);
    __syncthreads();
    for (int i = threadIdx.x; i < NBKT; i += 1024) {
        u32 c = hist[i];
        bhist[(size_t)blockIdx.x * NBKT + i] = c;
        if (c) atomicAdd(&gtotal[i], c);
    }
}

__global__ __launch_bounds__(256) void bin_scan(const u32* __restrict__ gtotal,
                                                u32* __restrict__ cbase,
                                                u32* __restrict__ gcursor) {
    __shared__ u32 sd[256];
    const int t = threadIdx.x;
    uint4 c = ((const uint4*)gtotal)[t];
    u32 s = c.x + c.y + c.z + c.w;
    sd[t] = s;
    __syncthreads();
    for (int off = 1; off < 256; off <<= 1) {
        u32 v = (t >= off) ? sd[t - off] : 0u;
        __syncthreads();
        sd[t] += v;
        __syncthreads();
    }
    u32 ex = sd[t] - s;
    u32 b0 = ex, b1 = ex + c.x, b2 = b1 + c.y, b3 = b2 + c.z;
    cbase[t * 4 + 0] = b0; gcursor[t * 4 + 0] = b0;
    cbase[t * 4 + 1] = b1; gcursor[t * 4 + 1] = b1;
    cbase[t * 4 + 2] = b2; gcursor[t * 4 + 2] = b2;
    cbase[t * 4 + 3] = b3; gcursor[t * 4 + 3] = b3;
    if (t == 255) cbase[NBKT] = N_EDGES_C;
}

__global__ __launch_bounds__(1024) void bin_scatter(const int* __restrict__ src,
                                                    const int* __restrict__ dst,
                                                    const u32* __restrict__ bhist,
                                                    u32* __restrict__ gcursor,
                                                    u32* __restrict__ packed) {
    __shared__ u32 gpos[NBKT];
    __shared__ u32 cur[NBKT];
    for (int i = threadIdx.x; i < NBKT; i += 1024) {
        u32 c = bhist[(size_t)blockIdx.x * NBKT + i];
        gpos[i] = c ? atomicAdd(&gcursor[i], c) : 0u;
        cur[i] = 0u;
    }
    __syncthreads();
    const int e0 = blockIdx.x * CHUNK;
    for (int i = threadIdx.x; i < CHUNK; i += 1024) {
        u32 d = (u32)dst[e0 + i];
        u32 b = d >> 8;
        u32 r = atomicAdd(&cur[b], 1u);
        packed[gpos[b] + r] = (u32)src[e0 + i] | ((d & 255u) << 18);
    }
}

__global__ __launch_bounds__(256) void csr_convert(const u32* __restrict__ cbase,
                                                   const u32* __restrict__ packed,
                                                   u32* __restrict__ row_start,
                                                   int* __restrict__ sorted_src) {
    __shared__ u32 cnt[NPB];
    __shared__ u32 pos[NPB];
    const int b = blockIdx.x;
    const u32 beg = cbase[b], end = cbase[b + 1];
    const int t = threadIdx.x;
    cnt[t] = 0u;
    __syncthreads();
    for (u32 i = beg + t; i < end; i += 256)
        atomicAdd(&cnt[packed[i] >> 18], 1u);
    __syncthreads();
    pos[t] = cnt[t];
    __syncthreads();
    for (int off = 1; off < 256; off <<= 1) {
        u32 v = (t >= off) ? pos[t - off] : 0u;
        __syncthreads();
        pos[t] += v;
        __syncthreads();
    }
    const u32 ex = pos[t] - cnt[t];
    row_start[b * NPB + t] = beg + ex;
    __syncthreads();
    cnt[t] = ex;
    __syncthreads();
    for (u32 i = beg + t; i < end; i += 256) {
        u32 p = packed[i];
        u32 r = atomicAdd(&cnt[p >> 18], 1u);
        sorted_src[beg + r] = (int)(p & 0x3FFFFu);
    }
    if (b == 0 && t == 0) row_start[N_NODES_C] = N_EDGES_C;
}

// ---------------- node transform via MFMA: h = X @ W, a_s, a_d ----------------
template <int LAYER>
__global__ __launch_bounds__(256) void transform_mfma(
    const void* __restrict__ xin_,
    const unsigned short* __restrict__ Wt,   // bf16 [64][64]: Wt[o][k]
    const float* __restrict__ att_s, const float* __restrict__ att_d,
    const float* __restrict__ bias_in,       // layer2 only: b1
    unsigned short* __restrict__ h_bf,
    float* __restrict__ a_s, float* __restrict__ a_d)
{
    const int lane = threadIdx.x & 63;
    const int wid  = threadIdx.x >> 6;
    const int col  = lane & 15;
    const int kl   = lane >> 4;   // 0..3

    short8 bfr[4][2];
    #pragma unroll
    for (int t = 0; t < 4; ++t)
        #pragma unroll
        for (int kh = 0; kh < 2; ++kh)
            bfr[t][kh] = *(const short8*)(Wt + (t * 16 + col) * 64 + kh * 32 + kl * 8);

    float attS[4], attD[4];
    #pragma unroll
    for (int t = 0; t < 4; ++t) {
        attS[t] = att_s[t * 16 + col];
        attD[t] = att_d[t * 16 + col];
    }
    float bofs[2][8];
    if constexpr (LAYER == 2) {
        #pragma unroll
        for (int kh = 0; kh < 2; ++kh)
            #pragma unroll
            for (int j = 0; j < 8; ++j) bofs[kh][j] = bias_in[kh * 32 + kl * 8 + j];
    }

    const int g = blockIdx.x * 4 + wid;
    const int arow = g * 16 + col;
    short8 af[2];
    if constexpr (LAYER == 1) {
        const float* xp = (const float*)xin_ + (size_t)arow * 64;
        #pragma unroll
        for (int kh = 0; kh < 2; ++kh) {
            f32x4 v0 = *(const f32x4*)(xp + kh * 32 + kl * 8);
            f32x4 v1 = *(const f32x4*)(xp + kh * 32 + kl * 8 + 4);
            short8 a;
            #pragma unroll
            for (int j = 0; j < 4; ++j) {
                a[j]     = (short)f2bf(v0[j]);
                a[4 + j] = (short)f2bf(v1[j]);
            }
            af[kh] = a;
        }
    } else {
        const unsigned short* xp = (const unsigned short*)xin_ + (size_t)arow * 64;
        #pragma unroll
        for (int kh = 0; kh < 2; ++kh) {
            short8 raw = *(const short8*)(xp + kh * 32 + kl * 8);
            short8 a;
            #pragma unroll
            for (int j = 0; j < 8; ++j)
                a[j] = (short)f2bf(bf2f((unsigned short)raw[j]) + bofs[kh][j]);
            af[kh] = a;
        }
    }

    f32x4 acc[4];
    #pragma unroll
    for (int t = 0; t < 4; ++t) {
        f32x4 d = {0.f, 0.f, 0.f, 0.f};
        d = __builtin_amdgcn_mfma_f32_16x16x32_bf16(af[0], bfr[t][0], d, 0, 0, 0);
        d = __builtin_amdgcn_mfma_f32_16x16x32_bf16(af[1], bfr[t][1], d, 0, 0, 0);
        acc[t] = d;
    }

    float ps[4] = {0.f, 0.f, 0.f, 0.f}, pd[4] = {0.f, 0.f, 0.f, 0.f};
    #pragma unroll
    for (int t = 0; t < 4; ++t) {
        #pragma unroll
        for (int j = 0; j < 4; ++j) {
            int node = g * 16 + kl * 4 + j;
            h_bf[(size_t)node * 64 + t * 16 + col] = f2bf(acc[t][j]);
            ps[j] += acc[t][j] * attS[t];
            pd[j] += acc[t][j] * attD[t];
        }
    }
    #pragma unroll
    for (int m = 1; m < 16; m <<= 1) {
        #pragma unroll
        for (int j = 0; j < 4; ++j) {
            ps[j] += __shfl_xor(ps[j], m, 64);
            pd[j] += __shfl_xor(pd[j], m, 64);
        }
    }
    if (col == 0) {
        #pragma unroll
        for (int j = 0; j < 4; ++j) {
            int node = g * 16 + kl * 4 + j;
            a_s[node] = ps[j];
            a_d[node] = pd[j];
        }
    }
}

// ---------------- per-node fallback (any degree) ----------------
static __device__ __forceinline__ void agg_one_node(
    int node, u32 beg, u32 end, int lane, int sub, int c4,
    const int* __restrict__ sorted_src, const float* __restrict__ a_s,
    const float* __restrict__ a_d, const unsigned short* __restrict__ h_bf,
    const float* __restrict__ bias_out, unsigned short* __restrict__ agg_bf)
{
    f32x4 acc = {0.f, 0.f, 0.f, 0.f};
    if (end > beg) {
        const float ad = a_d[node];
        float l = 0.f;
        for (u32 base = beg; base < end; base += 64) {
            u32 i = base + lane;
            bool valid = i < end;
            int s = valid ? sorted_src[i] : 0;
            float e = valid ? a_s[s] + ad : 0.f;
            e = e > 0.f ? e : NEG_SLOPE_C * e;
            float p = valid ? __expf(e) : 0.f;
            #pragma unroll
            for (int off = 32; off; off >>= 1) p += __shfl_xor(p, off, 64);
            l += p;
        }
        const float inv = 1.f / l;
        for (u32 base = beg; base < end; base += 64) {
            u32 i = base + lane;
            bool valid = i < end;
            int s = valid ? sorted_src[i] : 0;
            float e = valid ? a_s[s] + ad : 0.f;
            e = e > 0.f ? e : NEG_SLOPE_C * e;
            float p = valid ? __expf(e) * inv : 0.f;
            int c2 = (int)min(64u, end - base);
            for (int t = 0; t < c2; t += 4) {
                int j = t + sub;
                float al = __shfl(p, j, 64);     // unconditional
                int   sj = __shfl(s, j, 64);     // unconditional
                if (j >= c2) al = 0.f;
                us4 hv = *(const us4*)(h_bf + (size_t)sj * 64 + c4);
                acc[0] += al * bf2f(hv[0]);
                acc[1] += al * bf2f(hv[1]);
                acc[2] += al * bf2f(hv[2]);
                acc[3] += al * bf2f(hv[3]);
            }
        }
    }
    #pragma unroll
    for (int k = 0; k < 4; ++k) {
        acc[k] += __shfl_xor(acc[k], 16, 64);
        acc[k] += __shfl_xor(acc[k], 32, 64);
    }
    if (sub == 0) {
        us4 o;
        if (bias_out) {
            #pragma unroll
            for (int k = 0; k < 4; ++k) o[k] = f2bf(acc[k] + bias_out[c4 + k]);
        } else {
            #pragma unroll
            for (int k = 0; k < 4; ++k) o[k] = f2bf(acc[k]);
        }
        *(us4*)(agg_bf + (size_t)node * 64 + c4) = o;
    }
}

// ---------------- fused GAT aggregate: 3-tier (at gather floor) ----------------
__global__ __launch_bounds__(256) void gat_aggregate(
    const u32* __restrict__ row_start, const int* __restrict__ sorted_src,
    const float* __restrict__ a_s, const float* __restrict__ a_d,
    const unsigned short* __restrict__ h_bf, const float* __restrict__ bias_out,
    unsigned short* __restrict__ agg_bf)
{
    const int lane = threadIdx.x & 63;
    const int sub  = lane >> 4;        // slot = owned node index
    const int j    = lane & 15;        // slot-local edge / channel-quad index
    const int c4   = j * 4;            // channel quad base
    const int wid = (blockIdx.x * blockDim.x + threadIdx.x) >> 6;  // 65536 waves
    const int n0 = wid * 4;

    uint4 r4 = *(const uint4*)(row_start + n0);
    const u32 rs0 = r4.x, rs1 = r4.y, rs2 = r4.z, rs3 = r4.w;
    const u32 rs4 = row_start[n0 + 4];
    const int d0 = (int)(rs1 - rs0), d1 = (int)(rs2 - rs1);
    const int d2 = (int)(rs3 - rs2), d3 = (int)(rs4 - rs3);
    const int mx = max(max(d0, d1), max(d2, d3));
    const u32 beg = rs0, end = rs4;
    const int tot = (int)(end - beg);

    if (mx <= 16) {
        // ---- tier 1: slot-local softmax + per-slot-bounded PV ----
        const u32 rlo = (sub == 0) ? rs0 : (sub == 1) ? rs1 : (sub == 2) ? rs2 : rs3;
        const int ck  = (sub == 0) ? d0  : (sub == 1) ? d1  : (sub == 2) ? d2  : d3;
        const bool valid = j < ck;
        int s_own = valid ? sorted_src[rlo + j] : 0;
        float e = valid ? a_s[s_own] + a_d[n0 + sub] : 0.f;
        e = e > 0.f ? e : NEG_SLOPE_C * e;
        const float p = valid ? __expf(e) : 0.f;
        float l = p;
        l += __shfl_xor(l, 1, 64);
        l += __shfl_xor(l, 2, 64);
        l += __shfl_xor(l, 4, 64);
        l += __shfl_xor(l, 8, 64);
        const float alpha = valid ? p * (1.f / l) : 0.f;

        const int base = sub * 16;
        f32x4 acc = {0.f, 0.f, 0.f, 0.f};
        for (int t = 0; t < ck; t += 2) {
            float al0 = __shfl(alpha, base + t, 64);
            int   s0  = __shfl(s_own, base + t, 64);
            float al1 = __shfl(alpha, base + t + 1, 64);
            int   s1  = __shfl(s_own, base + t + 1, 64);
            if (t + 1 >= ck) al1 = 0.f;       // odd-ck guard (after shuffle)
            us4 h0 = *(const us4*)(h_bf + (size_t)s0 * 64 + c4);
            us4 h1 = *(const us4*)(h_bf + (size_t)s1 * 64 + c4);
            acc[0] += al0 * bf2f(h0[0]) + al1 * bf2f(h1[0]);
            acc[1] += al0 * bf2f(h0[1]) + al1 * bf2f(h1[1]);
            acc[2] += al0 * bf2f(h0[2]) + al1 * bf2f(h1[2]);
            acc[3] += al0 * bf2f(h0[3]) + al1 * bf2f(h1[3]);
        }

        us4 o;
        if (bias_out) {
            #pragma unroll
            for (int q = 0; q < 4; ++q) o[q] = f2bf(acc[q] + bias_out[c4 + q]);
        } else {
            #pragma unroll
            for (int q = 0; q < 4; ++q) o[q] = f2bf(acc[q]);
        }
        *(us4*)(agg_bf + (size_t)(n0 + sub) * 64 + c4) = o;
        return;
    }

    if (tot > 64) {
        agg_one_node(n0 + 0, rs0, rs1, lane, sub, c4, sorted_src, a_s, a_d, h_bf, bias_out, agg_bf);
        agg_one_node(n0 + 1, rs1, rs2, lane, sub, c4, sorted_src, a_s, a_d, h_bf, bias_out, agg_bf);
        agg_one_node(n0 + 2, rs2, rs3, lane, sub, c4, sorted_src, a_s, a_d, h_bf, bias_out, agg_bf);
        agg_one_node(n0 + 3, rs3, rs4, lane, sub, c4, sorted_src, a_s, a_d, h_bf, bias_out, agg_bf);
        return;
    }

    // ---- tier 2: union-lane path ----
    const u32 i = beg + (u32)lane;
    const bool valid = i < end;
    int s = valid ? sorted_src[i] : 0;
    const u32 r1 = rs1 - beg, r2 = rs2 - beg, r3 = rs3 - beg;
    const int nid = (int)((u32)lane >= r1) + (int)((u32)lane >= r2) + (int)((u32)lane >= r3);
    float e = valid ? a_s[s] + a_d[n0 + nid] : 0.f;
    e = e > 0.f ? e : NEG_SLOPE_C * e;
    const float p = valid ? __expf(e) : 0.f;

    float l0 = (nid == 0) ? p : 0.f;
    float l1 = (nid == 1) ? p : 0.f;
    float l2 = (nid == 2) ? p : 0.f;
    float l3 = (nid == 3) ? p : 0.f;
    #pragma unroll
    for (int off = 32; off; off >>= 1) {
        l0 += __shfl_xor(l0, off, 64);
        l1 += __shfl_xor(l1, off, 64);
        l2 += __shfl_xor(l2, off, 64);
        l3 += __shfl_xor(l3, off, 64);
    }
    const float i0 = 1.f / l0, i1 = 1.f / l1, i2 = 1.f / l2, i3 = 1.f / l3;
    const float invk = (nid < 2) ? (nid == 0 ? i0 : i1) : (nid == 2 ? i2 : i3);
    const float alpha = valid ? p * invk : 0.f;

    #pragma unroll
    for (int k = 0; k < 4; ++k) {
        const u32 rloK = (k == 0) ? rs0 : (k == 1) ? rs1 : (k == 2) ? rs2 : rs3;
        const u32 rhiK = (k == 0) ? rs1 : (k == 1) ? rs2 : (k == 2) ? rs3 : rs4;
        const int rb = (int)(rloK - beg);
        const int ck = (int)(rhiK - rloK);
        f32x4 acc = {0.f, 0.f, 0.f, 0.f};
        for (int t = 0; t < ck; t += 8) {
            const int j0 = rb + t + sub;
            const int j1 = j0 + 4;
            float al0 = __shfl(alpha, j0, 64);   // unconditional (convergent)
            int   s0  = __shfl(s, j0, 64);
            float al1 = __shfl(alpha, j1, 64);
            int   s1  = __shfl(s, j1, 64);
            if (t + sub >= ck)     al0 = 0.f;    // guard AFTER the shuffle
            if (t + 4 + sub >= ck) al1 = 0.f;
            us4 h0 = *(const us4*)(h_bf + (size_t)s0 * 64 + c4);
            us4 h1 = *(const us4*)(h_bf + (size_t)s1 * 64 + c4);
            acc[0] += al0 * bf2f(h0[0]) + al1 * bf2f(h1[0]);
            acc[1] += al0 * bf2f(h0[1]) + al1 * bf2f(h1[1]);
            acc[2] += al0 * bf2f(h0[2]) + al1 * bf2f(h1[2]);
            acc[3] += al0 * bf2f(h0[3]) + al1 * bf2f(h1[3]);
        }
        #pragma unroll
        for (int q = 0; q < 4; ++q) {
            acc[q] += __shfl_xor(acc[q], 16, 64);
            acc[q] += __shfl_xor(acc[q], 32, 64);
        }
        if (sub == 0) {
            us4 o;
            if (bias_out) {
                #pragma unroll
                for (int q = 0; q < 4; ++q) o[q] = f2bf(acc[q] + bias_out[c4 + q]);
            } else {
                #pragma unroll
                for (int q = 0; q < 4; ++q) o[q] = f2bf(acc[q]);
            }
            *(us4*)(agg_bf + (size_t)(n0 + k) * 64 + c4) = o;
        }
    }
}

// ---------------- FC head (fc1 + fc2 fused, 256 blocks x 1024 threads) ---------
// Block = 32 graphs. 16 waves = 4 col-groups x 4 K-quarters; each wave does
// 2 row-groups x 4 col-tiles = 8 MFMA per 6 loads (round-17 inner shape) with
// K-quarter = 512 (16 K-steps). kq>0 publish partials; kq==0 combines.
__global__ __launch_bounds__(1024) void fc_head(
    const unsigned short* __restrict__ agg_bf,
    const unsigned short* __restrict__ Wf1t,  // bf16 [256][2048]
    const float* __restrict__ bf1,
    const float* __restrict__ Wf2,            // [256][32]
    const float* __restrict__ bf2v,
    float* __restrict__ out)                  // [8192][32]
{
    __shared__ float shmem[3 * PREG];         // 3 partial regions (99 KB)
    const int lane = threadIdx.x & 63;
    const int w    = threadIdx.x >> 6;   // 0..15
    const int cg   = w & 3;              // col group: cols cg*64 .. +63
    const int kq   = w >> 2;             // K quarter 0..3
    const int col  = lane & 15;
    const int kl   = lane >> 4;
    const int rbase = blockIdx.x * 32;   // 256 blocks

    const int kbase = kq * 512 + kl * 8;
    const unsigned short* a0p = agg_bf + (size_t)(rbase + col) * 2048 + kbase;
    const unsigned short* a1p = a0p + 16 * 2048;
    const unsigned short* bp0 = Wf1t + (size_t)(cg * 64 + col) * 2048 + kbase;
    const unsigned short* bp1 = bp0 + 16 * 2048;
    const unsigned short* bp2 = bp0 + 32 * 2048;
    const unsigned short* bp3 = bp0 + 48 * 2048;

    f32x4 acc[2][4];
    #pragma unroll
    for (int rt = 0; rt < 2; ++rt)
        #pragma unroll
        for (int ct = 0; ct < 4; ++ct) acc[rt][ct] = (f32x4){0.f, 0.f, 0.f, 0.f};

    short8 a0 = *(const short8*)a0p, a1 = *(const short8*)a1p;
    short8 b0 = *(const short8*)bp0, b1 = *(const short8*)bp1;
    short8 b2 = *(const short8*)bp2, b3 = *(const short8*)bp3;

    for (int ks = 0; ks < 16; ++ks) {
        const short8 ca0 = a0, ca1 = a1, cb0 = b0, cb1 = b1, cb2 = b2, cb3 = b3;
        if (ks < 15) {                          // prefetch next K-step
            const int off = (ks + 1) * 32;
            a0 = *(const short8*)(a0p + off);
            a1 = *(const short8*)(a1p + off);
            b0 = *(const short8*)(bp0 + off);
            b1 = *(const short8*)(bp1 + off);
            b2 = *(const short8*)(bp2 + off);
            b3 = *(const short8*)(bp3 + off);
        }
        acc[0][0] = __builtin_amdgcn_mfma_f32_16x16x32_bf16(ca0, cb0, acc[0][0], 0, 0, 0);
        acc[1][0] = __builtin_amdgcn_mfma_f32_16x16x32_bf16(ca1, cb0, acc[1][0], 0, 0, 0);
        acc[0][1] = __builtin_amdgcn_mfma_f32_16x16x32_bf16(ca0, cb1, acc[0][1], 0, 0, 0);
        acc[1][1] = __builtin_amdgcn_mfma_f32_16x16x32_bf16(ca1, cb1, acc[1][1], 0, 0, 0);
        acc[0][2] = __builtin_amdgcn_mfma_f32_16x16x32_bf16(ca0, cb2, acc[0][2], 0, 0, 0);
        acc[1][2] = __builtin_amdgcn_mfma_f32_16x16x32_bf16(ca1, cb2, acc[1][2], 0, 0, 0);
        acc[0][3] = __builtin_amdgcn_mfma_f32_16x16x32_bf16(ca0, cb3, acc[0][3], 0, 0, 0);
        acc[1][3] = __builtin_amdgcn_mfma_f32_16x16x32_bf16(ca1, cb3, acc[1][3], 0, 0, 0);
    }

    // phase A: kq 1..3 publish partials
    if (kq > 0) {
        float* dst0 = shmem + (kq - 1) * PREG + cg * (64 * PSTR) + lane * PSTR;
        #pragma unroll
        for (int rt = 0; rt < 2; ++rt)
            #pragma unroll
            for (int ct = 0; ct < 4; ++ct)
                #pragma unroll
                for (int q = 0; q < 4; ++q)
                    dst0[rt * 16 + ct * 4 + q] = acc[rt][ct][q];
    }
    __syncthreads();
    // phase B: kq==0 combines 3 partials + bias + relu
    if (kq == 0) {
        const float* p0 = shmem + 0 * PREG + cg * (64 * PSTR) + lane * PSTR;
        const float* p1 = shmem + 1 * PREG + cg * (64 * PSTR) + lane * PSTR;
        const float* p2 = shmem + 2 * PREG + cg * (64 * PSTR) + lane * PSTR;
        #pragma unroll
        for (int rt = 0; rt < 2; ++rt) {
            #pragma unroll
            for (int ct = 0; ct < 4; ++ct) {
                const int ocol = cg * 64 + ct * 16 + col;
                const float bias = bf1[ocol];
                #pragma unroll
                for (int q = 0; q < 4; ++q) {
                    const int idx = rt * 16 + ct * 4 + q;
                    float v = acc[rt][ct][q] + p0[idx] + p1[idx] + p2[idx] + bias;
                    acc[rt][ct][q] = v > 0.f ? v : 0.f;
                }
            }
        }
    }
    __syncthreads();   // all partial reads done; shmem free for reuse
    // phase C: kq==0 writes f-rows (padded stride FSTR); 32*260 = 8320 floats
    if (kq == 0) {
        #pragma unroll
        for (int rt = 0; rt < 2; ++rt) {
            #pragma unroll
            for (int ct = 0; ct < 4; ++ct) {
                const int ocol = cg * 64 + ct * 16 + col;
                #pragma unroll
                for (int q = 0; q < 4; ++q) {
                    int row = rt * 16 + kl * 4 + q;   // block-relative 0..31
                    shmem[row * FSTR + ocol] = acc[rt][ct][q];
                }
            }
        }
    }
    __syncthreads();
    // phase D: fc2 — 1024 outputs, 1 per thread
    {
        const int b = threadIdx.x >> 5, o = threadIdx.x & 31;
        float a2 = bf2v[o];
        const float* fp = shmem + b * FSTR;
        for (int jj = 0; jj < 256; jj += 4) {
            a2 += fp[jj + 0] * Wf2[(jj + 0) * 32 + o];
            a2 += fp[jj + 1] * Wf2[(jj + 1) * 32 + o];
            a2 += fp[jj + 2] * Wf2[(jj + 2) * 32 + o];
            a2 += fp[jj + 3] * Wf2[(jj + 3) * 32 + o];
        }
        out[(size_t)(rbase + b) * 32 + o] = a2;
    }
}

// ---------------- launch ----------------
extern "C" void kernel_launch(void* const* d_in, const int* in_sizes, int n_in,
                              void* d_out, int out_size, void* d_ws, size_t ws_size,
                              hipStream_t stream)
{
    const float* x    = (const float*)d_in[0];
    const int*   ei   = (const int*)d_in[1];
    const float* W1   = (const float*)d_in[2];
    const float* as1  = (const float*)d_in[3];
    const float* ad1  = (const float*)d_in[4];
    const float* b1   = (const float*)d_in[5];
    const float* W2   = (const float*)d_in[6];
    const float* as2  = (const float*)d_in[7];
    const float* ad2  = (const float*)d_in[8];
    const float* b2   = (const float*)d_in[9];
    const float* Wf1  = (const float*)d_in[10];
    const float* bf1  = (const float*)d_in[11];
    const float* Wf2  = (const float*)d_in[12];
    const float* bf2v = (const float*)d_in[13];

    const int* src = ei;
    const int* dst = ei + N_EDGES_C;

    char* ws = (char*)d_ws;
    unsigned short* h_bf   = (unsigned short*)ws; ws += (size_t)N_NODES_C * 64 * 2;
    unsigned short* agg_bf = (unsigned short*)ws; ws += (size_t)N_NODES_C * 64 * 2;
    float* a_s          = (float*)ws;          ws += (size_t)N_NODES_C * 4;
    float* a_d          = (float*)ws;          ws += (size_t)N_NODES_C * 4;
    u32* row_start      = (u32*)ws;            ws += (size_t)(N_NODES_C + 4) * 4;
    int* sorted_src     = (int*)ws;            ws += (size_t)N_EDGES_C * 4;
    u32* packed         = (u32*)ws;            ws += (size_t)N_EDGES_C * 4;
    u32* bhist          = (u32*)ws;            ws += (size_t)NBINBLK * NBKT * 4;
    u32* gtotal         = (u32*)ws;            ws += NBKT * 4;
    u32* cbase          = (u32*)ws;            ws += (NBKT + 4) * 4;
    u32* gcursor        = (u32*)ws;            ws += NBKT * 4;
    unsigned short* Wt1 = (unsigned short*)ws; ws += 64 * 64 * 2;
    unsigned short* Wt2 = (unsigned short*)ws; ws += 64 * 64 * 2;
    unsigned short* Wf1t = (unsigned short*)ws; ws += (size_t)256 * 2048 * 2;

    // ---- weight transposes (bf16) ----
    transpose_cast<<<16, 256, 0, stream>>>(W1, Wt1, 64, 64);
    transpose_cast<<<16, 256, 0, stream>>>(W2, Wt2, 64, 64);
    transpose_cast<<<2048, 256, 0, stream>>>(Wf1, Wf1t, 2048, 256);

    // ---- CSR build: block-owned bucket sort (shared by both layers) ----
    zero_u32<<<1, 256, 0, stream>>>(gtotal, NBKT);
    bin_count<<<NBINBLK, 1024, 0, stream>>>(dst, gtotal, bhist);
    bin_scan<<<1, 256, 0, stream>>>(gtotal, cbase, gcursor);
    bin_scatter<<<NBINBLK, 1024, 0, stream>>>(src, dst, bhist, gcursor, packed);
    csr_convert<<<NBKT, 256, 0, stream>>>(cbase, packed, row_start, sorted_src);

    // ---- layer 1 ----
    transform_mfma<1><<<4096, 256, 0, stream>>>(x, Wt1, as1, ad1, nullptr, h_bf, a_s, a_d);
    gat_aggregate<<<16384, 256, 0, stream>>>(row_start, sorted_src, a_s, a_d, h_bf,
                                             nullptr, agg_bf);

    // ---- layer 2 (fold b2 into aggregate output for fc1) ----
    transform_mfma<2><<<4096, 256, 0, stream>>>(agg_bf, Wt2, as2, ad2, b1, h_bf, a_s, a_d);
    gat_aggregate<<<16384, 256, 0, stream>>>(row_start, sorted_src, a_s, a_d, h_bf,
                                             b2, agg_bf);

    // ---- FC head (fc1 + fc2 fused) ----
    fc_head<<<256, 1024, 0, stream>>>(agg_bf, Wf1t, bf1, Wf2, bf2v, (float*)d_out);
}